// Round 5
// baseline (162.819 us; speedup 1.0000x reference)
//
#include <hip/hip_runtime.h>
#include <cstdint>
#include <cstddef>

#define B 64
#define S 2048
#define D 512
#define H 128
#define Q 4
#define QH 32
#define KTOP 4
#define NROWS (B * S)
#define NEGV -1e9f
#define RPB 128                 // rows per block (fused)
#define NBLK (NROWS / RPB)      // 1024
#define CPB (S / RPB)           // 16 chunks per b

typedef __bf16 bf16x8 __attribute__((ext_vector_type(8)));
typedef float f32x4 __attribute__((ext_vector_type(4)));
typedef unsigned short us8 __attribute__((ext_vector_type(8)));

// ---------------------------------------------------------------------------
// helpers
// ---------------------------------------------------------------------------
__device__ __forceinline__ unsigned hasbyte(unsigned v, unsigned c) {
    unsigned x = v ^ (c * 0x01010101u);
    return (x - 0x01010101u) & ~x & 0x80808080u;
}

__device__ __forceinline__ unsigned short rnbf(float x) {
    unsigned u = __float_as_uint(x);
    unsigned r = u + 0x7FFFu + ((u >> 16) & 1u);  // round-to-nearest-even bf16
    return (unsigned short)(r >> 16);
}

__device__ __forceinline__ void split_rn(float x, unsigned short& hi, unsigned short& lo) {
    hi = rnbf(x);
    float fh = __uint_as_float((unsigned)hi << 16);
    lo = rnbf(x - fh);
}

__device__ __forceinline__ float tanh_f(float x) {
    float e = __expf(2.f * x);
    return 1.f - __fdividef(2.f, e + 1.f);
}

// ---------------------------------------------------------------------------
// K0: blocks 0..255 split W1 into transposed bf16 hi/lo planes [h][k] (RN);
//     block 256 detects mask dtype. modes: 0=u8,1=i32,2=i64,3=f32,4=f64
// ---------------------------------------------------------------------------
__global__ __launch_bounds__(256) void prep_kernel(
    const float* __restrict__ W1, unsigned short* __restrict__ bh,
    unsigned short* __restrict__ bl, const unsigned char* __restrict__ m,
    int* __restrict__ mode) {
    const int t = threadIdx.x;
    if (blockIdx.x < 256) {
        int i = blockIdx.x * 256 + t;  // i = h*512 + k
        int h = i >> 9, k = i & 511;
        float x = W1[(size_t)k * H + h];
        unsigned short hv, lv;
        split_rn(x, hv, lv);
        bh[i] = hv;
        bl[i] = lv;
        return;
    }
    __shared__ int fF0, fF, fB, fO4;
    if (t == 0) { fF0 = 0; fF = 0; fB = 0; fO4 = 0; }
    __syncthreads();
    const uint4* mv = (const uint4*)m;
    int a = 0, bb = 0, c = 0, d = 0;
    for (int i = t; i < NROWS / 16; i += 256) {
        uint4 v = mv[i];
        if (hasbyte(v.x, 0xF0u) | hasbyte(v.y, 0xF0u) | hasbyte(v.z, 0xF0u) | hasbyte(v.w, 0xF0u)) a = 1;
        if (hasbyte(v.x, 0x3Fu) | hasbyte(v.y, 0x3Fu) | hasbyte(v.z, 0x3Fu) | hasbyte(v.w, 0x3Fu) |
            hasbyte(v.x, 0x80u) | hasbyte(v.y, 0x80u) | hasbyte(v.z, 0x80u) | hasbyte(v.w, 0x80u)) bb = 1;
        if ((v.x & 0xFFFFFF00u) | (v.y & 0xFFFFFF00u) | (v.z & 0xFFFFFF00u) | (v.w & 0xFFFFFF00u)) c = 1;
        if ((v.y & 0xFFu) | (v.w & 0xFFu)) d = 1;
    }
    if (a) atomicOr(&fF0, 1);
    if (bb) atomicOr(&fF, 1);
    if (c) atomicOr(&fB, 1);
    if (d) atomicOr(&fO4, 1);
    __syncthreads();
    if (t == 0) {
        int md;
        if (fF0) md = 4;
        else if (fF) md = 3;
        else if (fB) md = 0;
        else if (fO4) md = 1;
        else md = 2;
        *mode = md;
    }
}

// ---------------------------------------------------------------------------
// K1 (one-pass fused): split-bf16-MFMA evidence + epilogue (tanh/w2, quality
// MLP, mask, comb, ew, Zpart) + pooling partials FROM LDS-PERSISTENT A-hi.
// 128 rows x 128 h per block, BK=32 x 16 chunks, 512 thr = 8 waves (2x2x...).
// A-hi persists in LDS for all 16 K-chunks: feats read from HBM exactly once.
// ---------------------------------------------------------------------------
__global__ __launch_bounds__(512) void fused_kernel(
    const float* __restrict__ feats, const unsigned short* __restrict__ wbh,
    const unsigned short* __restrict__ wbl, const float* __restrict__ b1g,
    const float* __restrict__ w2g, const float* __restrict__ b2g,
    const void* __restrict__ mraw, const int* __restrict__ mode,
    const float* __restrict__ segq, const float* __restrict__ qW1,
    const float* __restrict__ qb1, const float* __restrict__ qw2,
    const float* __restrict__ qb2, float* __restrict__ comb,
    float* __restrict__ Zpart, float* __restrict__ part) {
    __shared__ unsigned short Ah[16][RPB][32];  // 128 KiB, persistent, swizzled
    __shared__ unsigned short Al[RPB][32];      // 8 KiB, per-chunk
    __shared__ unsigned short Bh[H][32];        // 8 KiB, per-chunk, swizzled
    __shared__ unsigned short Bl[H][32];        // 8 KiB
    __shared__ float red[RPB][2];
    __shared__ float sew[RPB];
    __shared__ float sQW[Q * QH];
    __shared__ float sQb1[QH];
    __shared__ float sQw2[QH];
    __shared__ float sQb2;

    const int t = threadIdx.x;
    const int lane = t & 63;
    const int wid = t >> 6;       // 0..7
    const int wm = wid >> 1;      // 0..3: row group of 32
    const int wn = wid & 1;       // 0..1: h half of 64
    const int l16 = lane & 15, lk = lane >> 4;
    const int row0 = blockIdx.x * RPB;
    const int md = *mode;

    if (t < Q * QH) sQW[t] = qW1[t];
    else if (t < 160) sQb1[t - 128] = qb1[t - 128];
    else if (t < 192) sQw2[t - 160] = qw2[t - 160];
    else if (t == 192) sQb2 = qb2[0];

    // staging maps: thread -> (row/h = t>>2, k-octet o = t&3), swizzled pos po
    const int ar = t >> 2;
    const int o = t & 3;
    const int po = o ^ ((ar >> 1) & 3);
    const float* fsrc = feats + (size_t)(row0 + ar) * D + o * 8;
    const unsigned short* bsrch = wbh + (size_t)ar * D + o * 8;
    const unsigned short* bsrcl = wbl + (size_t)ar * D + o * 8;

    f32x4 acc[2][4];
#pragma unroll
    for (int mf = 0; mf < 2; ++mf)
#pragma unroll
        for (int nf = 0; nf < 4; ++nf) acc[mf][nf] = (f32x4)0.f;

    // ---- prologue: stage chunk 0 ----
    float rA[8];
    us8 rBh, rBl;
    *reinterpret_cast<float4*>(&rA[0]) = *reinterpret_cast<const float4*>(fsrc + 0);
    *reinterpret_cast<float4*>(&rA[4]) = *reinterpret_cast<const float4*>(fsrc + 4);
    rBh = *reinterpret_cast<const us8*>(bsrch);
    rBl = *reinterpret_cast<const us8*>(bsrcl);
    {
        us8 vh, vl;
#pragma unroll
        for (int j = 0; j < 8; ++j) {
            unsigned short hh, ll;
            split_rn(rA[j], hh, ll);
            vh[j] = hh; vl[j] = ll;
        }
        *reinterpret_cast<us8*>(&Ah[0][ar][po * 8]) = vh;
        *reinterpret_cast<us8*>(&Al[ar][po * 8]) = vl;
        *reinterpret_cast<us8*>(&Bh[ar][po * 8]) = rBh;
        *reinterpret_cast<us8*>(&Bl[ar][po * 8]) = rBl;
    }

    // ---- K loop: 16 chunks, 2 barriers each, prefetch under MFMA ----
    for (int kci = 0; kci < 16; ++kci) {
        __syncthreads();  // staged tiles for kci visible
        if (kci < 15) {   // issue next-chunk loads; waited only at next barrier
            const int kc = (kci + 1) * 32;
            *reinterpret_cast<float4*>(&rA[0]) = *reinterpret_cast<const float4*>(fsrc + kc);
            *reinterpret_cast<float4*>(&rA[4]) = *reinterpret_cast<const float4*>(fsrc + kc + 4);
            rBh = *reinterpret_cast<const us8*>(bsrch + kc);
            rBl = *reinterpret_cast<const us8*>(bsrcl + kc);
        }
        bf16x8 ah[2], al[2], bh[4], bl[4];
#pragma unroll
        for (int mf = 0; mf < 2; ++mf) {
            int rr = wm * 32 + mf * 16 + l16;
            int sp = (lk ^ ((rr >> 1) & 3)) * 8;
            ah[mf] = *reinterpret_cast<const bf16x8*>(&Ah[kci][rr][sp]);
            al[mf] = *reinterpret_cast<const bf16x8*>(&Al[rr][sp]);
        }
#pragma unroll
        for (int nf = 0; nf < 4; ++nf) {
            int hh = wn * 64 + nf * 16 + l16;
            int sp = (lk ^ ((hh >> 1) & 3)) * 8;
            bh[nf] = *reinterpret_cast<const bf16x8*>(&Bh[hh][sp]);
            bl[nf] = *reinterpret_cast<const bf16x8*>(&Bl[hh][sp]);
        }
#pragma unroll
        for (int mf = 0; mf < 2; ++mf)
#pragma unroll
            for (int nf = 0; nf < 4; ++nf) {
                acc[mf][nf] = __builtin_amdgcn_mfma_f32_16x16x32_bf16(ah[mf], bh[nf], acc[mf][nf], 0, 0, 0);
                acc[mf][nf] = __builtin_amdgcn_mfma_f32_16x16x32_bf16(ah[mf], bl[nf], acc[mf][nf], 0, 0, 0);
                acc[mf][nf] = __builtin_amdgcn_mfma_f32_16x16x32_bf16(al[mf], bh[nf], acc[mf][nf], 0, 0, 0);
            }
        __syncthreads();  // frag reads done; prefetch landed (vmcnt drained)
        if (kci < 15) {
            us8 vh, vl;
#pragma unroll
            for (int j = 0; j < 8; ++j) {
                unsigned short hh, ll;
                split_rn(rA[j], hh, ll);
                vh[j] = hh; vl[j] = ll;
            }
            *reinterpret_cast<us8*>(&Ah[kci + 1][ar][po * 8]) = vh;
            *reinterpret_cast<us8*>(&Al[ar][po * 8]) = vl;
            *reinterpret_cast<us8*>(&Bh[ar][po * 8]) = rBh;
            *reinterpret_cast<us8*>(&Bl[ar][po * 8]) = rBl;
        }
    }

    // ---- epilogue: tanh + w2 dot, reduce over 16 col-lanes ----
    float b1v[4], w2v[4];
#pragma unroll
    for (int nf = 0; nf < 4; ++nf) {
        int hh = wn * 64 + nf * 16 + l16;
        b1v[nf] = b1g[hh];
        w2v[nf] = w2g[hh];
    }
#pragma unroll
    for (int mf = 0; mf < 2; ++mf)
#pragma unroll
        for (int r2 = 0; r2 < 4; ++r2) {
            float s = 0.f;
#pragma unroll
            for (int nf = 0; nf < 4; ++nf) s += tanh_f(acc[mf][nf][r2] + b1v[nf]) * w2v[nf];
            s += __shfl_xor(s, 1, 16);
            s += __shfl_xor(s, 2, 16);
            s += __shfl_xor(s, 4, 16);
            s += __shfl_xor(s, 8, 16);
            if (l16 == 0) red[wm * 32 + mf * 16 + lk * 4 + r2][wn] = s;
        }
    __syncthreads();

    // ---- per-row: quality MLP + mask decode + comb + ew ----
    if (t < RPB) {
        const int row = row0 + t;
        float4 sq = *reinterpret_cast<const float4*>(&segq[(size_t)row * Q]);
        float q = sQb2;
#pragma unroll
        for (int h = 0; h < QH; ++h) {
            float a = sq.x * sQW[h] + sq.y * sQW[QH + h] + sq.z * sQW[2 * QH + h] + sq.w * sQW[3 * QH + h] + sQb1[h];
            q += fmaxf(a, 0.f) * sQw2[h];
        }
        float mv;
        switch (md) {
            case 0: mv = ((const unsigned char*)mraw)[row] ? 1.f : 0.f; break;
            case 1: mv = ((const int*)mraw)[row] ? 1.f : 0.f; break;
            case 2: mv = ((const long long*)mraw)[row] ? 1.f : 0.f; break;
            case 3: mv = (((const float*)mraw)[row] != 0.f) ? 1.f : 0.f; break;
            default: mv = (((const double*)mraw)[row] != 0.0) ? 1.f : 0.f; break;
        }
        float e = red[t][0] + red[t][1] + b2g[0];
        float c = (mv != 0.f) ? (e + q) : NEGV;
        comb[row] = c;
        sew[t] = __expf(c);  // exp(-1e9) flushes to 0
    }
    __syncthreads();

    // ---- Zpart (wave 0) ----
    if (t < 64) {
        float z = sew[t] + sew[t + 64];
#pragma unroll
        for (int oo = 32; oo > 0; oo >>= 1) z += __shfl_xor(z, oo, 64);
        if (t == 0) Zpart[blockIdx.x] = z;
    }

    // ---- pooling partials from LDS-persistent A-hi (no HBM re-read) ----
    if (t < 256) {
        const int d0 = t * 2;
        const int kci = d0 >> 5;
        const int c = d0 & 31;          // even
        const int og = c >> 3, c7 = c & 7;
        float a0 = 0.f, a1 = 0.f;
#pragma unroll 8
        for (int r = 0; r < RPB; ++r) {
            const int row = (r + kci) & (RPB - 1);  // stagger: 2-way banks
            const int sp = (og ^ ((row >> 1) & 3)) * 8 + c7;
            unsigned v = *reinterpret_cast<const unsigned*>(&Ah[kci][row][sp]);
            float f0 = __uint_as_float((v & 0xFFFFu) << 16);
            float f1 = __uint_as_float(v & 0xFFFF0000u);
            float w = sew[row];
            a0 += w * f0;
            a1 += w * f1;
        }
        float2 o2 = make_float2(a0, a1);
        *reinterpret_cast<float2*>(&part[(size_t)blockIdx.x * D + d0]) = o2;
    }
}

// ---------------------------------------------------------------------------
// K2: per-b finalize: Z, weights=exp(comb)/Z, top-4, part-reduce, gather, mix
// ---------------------------------------------------------------------------
__global__ __launch_bounds__(256) void finalize_kernel(
    const float* __restrict__ comb, const float* __restrict__ Zpart,
    const float* __restrict__ part, const float* __restrict__ feats,
    float* __restrict__ o_weights, float* __restrict__ o_tidx, float* __restrict__ o_tval,
    float* __restrict__ o_attn, float* __restrict__ o_topk, float* __restrict__ o_pooled) {
    __shared__ float sinv;
    __shared__ float mvv[256 * 4];
    __shared__ int mii[256 * 4];
    __shared__ int sti[4];
    __shared__ float stv[4];
    __shared__ float sdn;
    const int b = blockIdx.x, t = threadIdx.x;
    const float* row = comb + (size_t)b * S;

    if (t == 0) {
        float z = 0.f;
#pragma unroll
        for (int j = 0; j < CPB; ++j) z += Zpart[b * CPB + j];
        sinv = 1.f / fmaxf(z, 1e-8f);
    }
    __syncthreads();
    const float inv = sinv;

    float tv[4] = {-3e38f, -3e38f, -3e38f, -3e38f};
    int ti[4] = {1 << 30, 1 << 30, 1 << 30, 1 << 30};
    for (int s = t; s < S; s += 256) {
        float v = row[s];
        o_weights[(size_t)b * S + s] = __expf(v) * inv;
        if (v > tv[3]) {
            tv[3] = v; ti[3] = s;
#pragma unroll
            for (int k = 3; k > 0; --k) {
                bool up = (tv[k] > tv[k - 1]) || (tv[k] == tv[k - 1] && ti[k] < ti[k - 1]);
                if (up) {
                    float fv = tv[k]; tv[k] = tv[k - 1]; tv[k - 1] = fv;
                    int ii = ti[k]; ti[k] = ti[k - 1]; ti[k - 1] = ii;
                }
            }
        }
    }
#pragma unroll
    for (int k = 0; k < 4; ++k) { mvv[t * 4 + k] = tv[k]; mii[t * 4 + k] = ti[k]; }
    __syncthreads();
    for (int st = 128; st >= 1; st >>= 1) {
        if (t < st) {
            float av[4], bv[4];
            int ai[4], bi[4];
#pragma unroll
            for (int k = 0; k < 4; ++k) {
                av[k] = mvv[t * 4 + k]; ai[k] = mii[t * 4 + k];
                bv[k] = mvv[(t + st) * 4 + k]; bi[k] = mii[(t + st) * 4 + k];
            }
            float rv[4]; int ri[4];
            int i = 0, j = 0;
            for (int oo = 0; oo < 4; ++oo) {
                bool ta = (av[i] > bv[j]) || (av[i] == bv[j] && ai[i] < bi[j]);
                if (ta) { rv[oo] = av[i]; ri[oo] = ai[i]; ++i; }
                else { rv[oo] = bv[j]; ri[oo] = bi[j]; ++j; }
            }
#pragma unroll
            for (int k = 0; k < 4; ++k) { mvv[t * 4 + k] = rv[k]; mii[t * 4 + k] = ri[k]; }
        }
        __syncthreads();
    }
    if (t == 0) {
        float dn = 0.f;
#pragma unroll
        for (int k = 0; k < 4; ++k) {
            int idx = mii[k];
            int valid = (mvv[k] > -1e8f) ? 1 : 0;
            sti[k] = idx;
            stv[k] = (float)valid;
            o_tidx[b * 4 + k] = (float)idx;
            o_tval[b * 4 + k] = (float)valid;
            dn += (float)valid;
        }
        sdn = fmaxf(dn, 1.f);
    }
    __syncthreads();

    const int i0 = sti[0], i1 = sti[1], i2 = sti[2], i3 = sti[3];
    const float v0 = stv[0], v1 = stv[1], v2 = stv[2], v3 = stv[3];
    const float inv_dn = 1.f / sdn;
    for (int d = t; d < D; d += 256) {
        float s = 0.f;
#pragma unroll
        for (int ch = 0; ch < CPB; ++ch) s += part[((size_t)(b * CPB + ch)) * D + d];
        s *= inv;
        float tk = v0 * feats[((size_t)b * S + i0) * D + d] + v1 * feats[((size_t)b * S + i1) * D + d] +
                   v2 * feats[((size_t)b * S + i2) * D + d] + v3 * feats[((size_t)b * S + i3) * D + d];
        tk *= inv_dn;
        o_attn[(size_t)b * D + d] = s;
        o_topk[(size_t)b * D + d] = tk;
        o_pooled[(size_t)b * D + d] = 0.5f * s + 0.5f * tk;
    }
}

// ---------------------------------------------------------------------------
extern "C" void kernel_launch(void* const* d_in, const int* in_sizes, int n_in,
                              void* d_out, int out_size, void* d_ws, size_t ws_size,
                              hipStream_t stream) {
    const float* feats = (const float*)d_in[0];
    const void* maskraw = d_in[1];
    const float* segq = (const float*)d_in[2];
    const float* W1 = (const float*)d_in[3];
    const float* b1 = (const float*)d_in[4];
    const float* w2 = (const float*)d_in[5];
    const float* b2 = (const float*)d_in[6];
    const float* qW1 = (const float*)d_in[7];
    const float* qb1 = (const float*)d_in[8];
    const float* qw2 = (const float*)d_in[9];
    const float* qb2 = (const float*)d_in[10];

    char* ws = (char*)d_ws;
    int* mode = (int*)ws;                         // 16 B
    float* comb = (float*)(ws + 16);              // B*S
    float* part = comb + NROWS;                   // NBLK*D (2 MiB)
    float* Zpart = part + (size_t)NBLK * D;       // NBLK
    unsigned short* wsBh = (unsigned short*)(Zpart + NBLK);  // H*D
    unsigned short* wsBl = wsBh + (size_t)H * D;

    float* out = (float*)d_out;
    float* o_pooled = out;                        // B*D
    float* o_weights = out + (size_t)B * D;       // B*S
    float* o_attn = o_weights + (size_t)B * S;    // B*D
    float* o_topk = o_attn + (size_t)B * D;       // B*D
    float* o_tidx = o_topk + (size_t)B * D;       // B*K
    float* o_tval = o_tidx + (size_t)B * KTOP;    // B*K

    prep_kernel<<<257, 256, 0, stream>>>(W1, wsBh, wsBl, (const unsigned char*)maskraw, mode);
    fused_kernel<<<NBLK, 512, 0, stream>>>(
        feats, wsBh, wsBl, b1, w2, b2, maskraw, mode, segq, qW1, qb1, qw2, qb2,
        comb, Zpart, part);
    finalize_kernel<<<B, 256, 0, stream>>>(comb, Zpart, part, feats, o_weights,
                                           o_tidx, o_tval, o_attn, o_topk, o_pooled);
}